// Round 3
// baseline (152.264 us; speedup 1.0000x reference)
//
#include <hip/hip_runtime.h>
#include <hip/hip_bf16.h>
#include <stdint.h>

// Problem constants
#define B_ 32
#define L_ 512
#define I_ 1024
#define O_ 1024
#define NSTEP (I_ / 32)   // 32 K-steps of BK=32

typedef float  f32x4  __attribute__((ext_vector_type(4)));
typedef __bf16 bf16x8 __attribute__((ext_vector_type(8)));

__device__ __forceinline__ bf16x8 cvt8(f32x4 a, f32x4 b) {
    bf16x8 r;
    r[0] = (__bf16)a[0]; r[1] = (__bf16)a[1]; r[2] = (__bf16)a[2]; r[3] = (__bf16)a[3];
    r[4] = (__bf16)b[0]; r[5] = (__bf16)b[1]; r[6] = (__bf16)b[2]; r[7] = (__bf16)b[3];
    return r;
}

// ---- Pass 0: sigma = exp(0.5 * logvar), 4 MiB, reused by all 32 batches ----
__global__ void gen_sigma(const float* __restrict__ wlv, float* __restrict__ sig) {
    const int i = blockIdx.x * blockDim.x + threadIdx.x;   // exactly O*I/4 threads
    const f32x4 l = *(const f32x4*)(wlv + (size_t)i * 4);
    f32x4 s;
    s[0] = __expf(0.5f * l[0]); s[1] = __expf(0.5f * l[1]);
    s[2] = __expf(0.5f * l[2]); s[3] = __expf(0.5f * l[3]);
    *(f32x4*)(sig + (size_t)i * 4) = s;
}

// ---- Fused: C[b] = X[b] * (mean + noise[b]*sigma)^T + bias ----
// 128x128 tile, BK=32, 4 waves (2x2, 64x64 each), LDS double-buffer,
// reg-staged prefetch: loads for tile t+1 issued before MFMA of tile t,
// transform+ds_write after MFMA, ONE barrier per iteration.
template<bool SIGMA>
__global__ __launch_bounds__(256) void fused_gemm(
    const float* __restrict__ x, const float* __restrict__ wmean,
    const float* __restrict__ sig,   // sigma if SIGMA, else raw logvar
    const float* __restrict__ bias, const float* __restrict__ noise,
    float* __restrict__ out)
{
    __shared__ __bf16 As[2][128 * 32];   // 8 KB each buf
    __shared__ __bf16 Bs[2][128 * 32];   // total LDS = 32 KB

    // XCD swizzle (1024 % 8 == 0 -> simple bijective): 128 consecutive logical
    // blocks per XCD. Logical order: batch-major, nt outer, mt inner, so the
    // 4 blocks sharing a noise panel are adjacent (L2 reuse), and one batch's
    // x slice (2 MB) stays L2-resident.
    const int bid = ((int)blockIdx.x & 7) * 128 + ((int)blockIdx.x >> 3);
    const int b   = bid >> 5;
    const int nt  = (bid >> 2) & 7;
    const int mt  = bid & 3;

    const int t    = threadIdx.x;
    const int wave = t >> 6, lane = t & 63;
    const int wr   = wave >> 1, wc = wave & 1;
    const int hr   = lane & 15, kq = lane >> 4;

    // staging geometry: chunk t -> row t>>2, 8-col group t&3; chunk t+256 -> row+64.
    // ds_write byte address = chunk*16 -> linear in lane order, conflict-free.
    const int r1 = t >> 2, q1 = t & 3;
    const float* xp = x     + (size_t)b * L_ * I_ + (size_t)(mt * 128 + r1) * I_ + q1 * 8;
    const float* np = noise + (size_t)b * O_ * I_ + (size_t)(nt * 128 + r1) * I_ + q1 * 8;
    const float* mp = wmean + (size_t)(nt * 128 + r1) * I_ + q1 * 8;
    const float* sp = sig   + (size_t)(nt * 128 + r1) * I_ + q1 * 8;
    const size_t half = (size_t)64 * I_;   // chunk2 = same col group, row+64

    f32x4 acc[4][4];
    #pragma unroll
    for (int m = 0; m < 4; ++m)
        #pragma unroll
        for (int n = 0; n < 4; ++n)
            acc[m][n] = (f32x4)(0.0f);

    f32x4 ax[4], nz[4];          // streaming prefetch regs (x, noise)

    // prologue: load + transform + write buf 0
    {
        #pragma unroll
        for (int j = 0; j < 2; ++j) {
            ax[2*j]   = *(const f32x4*)(xp + j*half);
            ax[2*j+1] = *(const f32x4*)(xp + j*half + 4);
            nz[2*j]   = *(const f32x4*)(np + j*half);
            nz[2*j+1] = *(const f32x4*)(np + j*half + 4);
        }
        f32x4 mm[4], ss[4];
        #pragma unroll
        for (int j = 0; j < 2; ++j) {
            mm[2*j]   = *(const f32x4*)(mp + j*half);
            mm[2*j+1] = *(const f32x4*)(mp + j*half + 4);
            ss[2*j]   = *(const f32x4*)(sp + j*half);
            ss[2*j+1] = *(const f32x4*)(sp + j*half + 4);
        }
        *(bf16x8*)&As[0][t * 8]        = cvt8(ax[0], ax[1]);
        *(bf16x8*)&As[0][t * 8 + 2048] = cvt8(ax[2], ax[3]);
        f32x4 w[4];
        #pragma unroll
        for (int j = 0; j < 4; ++j) {
            #pragma unroll
            for (int e = 0; e < 4; ++e) {
                const float sg = SIGMA ? ss[j][e] : __expf(0.5f * ss[j][e]);
                w[j][e] = mm[j][e] + nz[j][e] * sg;
            }
        }
        *(bf16x8*)&Bs[0][t * 8]        = cvt8(w[0], w[1]);
        *(bf16x8*)&Bs[0][t * 8 + 2048] = cvt8(w[2], w[3]);
    }
    __syncthreads();

    int cur = 0;
    for (int it = 0; it < NSTEP; ++it) {
        const int k0n = (it + 1) * 32;

        // (1) issue next tile's streaming loads (x, noise) — overlap with MFMA
        if (it + 1 < NSTEP) {
            #pragma unroll
            for (int j = 0; j < 2; ++j) {
                ax[2*j]   = *(const f32x4*)(xp + k0n + j*half);
                ax[2*j+1] = *(const f32x4*)(xp + k0n + j*half + 4);
                nz[2*j]   = *(const f32x4*)(np + k0n + j*half);
                nz[2*j+1] = *(const f32x4*)(np + k0n + j*half + 4);
            }
        }

        // (2) LDS -> frags -> MFMA on current buffer
        bf16x8 af[4], bfr[4];
        #pragma unroll
        for (int m = 0; m < 4; ++m)
            af[m] = *(const bf16x8*)&As[cur][(wr * 64 + m * 16 + hr) * 32 + kq * 8];
        #pragma unroll
        for (int n = 0; n < 4; ++n)
            bfr[n] = *(const bf16x8*)&Bs[cur][(wc * 64 + n * 16 + hr) * 32 + kq * 8];
        #pragma unroll
        for (int m = 0; m < 4; ++m)
            #pragma unroll
            for (int n = 0; n < 4; ++n)
                acc[m][n] = __builtin_amdgcn_mfma_f32_16x16x32_bf16(af[m], bfr[n], acc[m][n], 0, 0, 0);

        // (3) transform + write NEXT buffer (mean/sigma are L2/L3-hot), one barrier
        if (it + 1 < NSTEP) {
            f32x4 mm[4], ss[4];
            #pragma unroll
            for (int j = 0; j < 2; ++j) {
                mm[2*j]   = *(const f32x4*)(mp + k0n + j*half);
                mm[2*j+1] = *(const f32x4*)(mp + k0n + j*half + 4);
                ss[2*j]   = *(const f32x4*)(sp + k0n + j*half);
                ss[2*j+1] = *(const f32x4*)(sp + k0n + j*half + 4);
            }
            const int nxt = cur ^ 1;
            *(bf16x8*)&As[nxt][t * 8]        = cvt8(ax[0], ax[1]);
            *(bf16x8*)&As[nxt][t * 8 + 2048] = cvt8(ax[2], ax[3]);
            f32x4 w[4];
            #pragma unroll
            for (int j = 0; j < 4; ++j) {
                #pragma unroll
                for (int e = 0; e < 4; ++e) {
                    const float sg = SIGMA ? ss[j][e] : __expf(0.5f * ss[j][e]);
                    w[j][e] = mm[j][e] + nz[j][e] * sg;
                }
            }
            *(bf16x8*)&Bs[nxt][t * 8]        = cvt8(w[0], w[1]);
            *(bf16x8*)&Bs[nxt][t * 8 + 2048] = cvt8(w[2], w[3]);
            __syncthreads();
            cur = nxt;
        }
    }

    // epilogue (validated R1/R2): C/D layout col=lane&15, row=(lane>>4)*4+reg
    float* ob = out + (size_t)b * L_ * O_;
    #pragma unroll
    for (int n = 0; n < 4; ++n) {
        const int col = nt * 128 + wc * 64 + n * 16 + hr;
        const float bv = bias[col];
        #pragma unroll
        for (int m = 0; m < 4; ++m) {
            const int row0 = mt * 128 + wr * 64 + m * 16 + kq * 4;
            #pragma unroll
            for (int j = 0; j < 4; ++j)
                ob[(size_t)(row0 + j) * O_ + col] = acc[m][n][j] + bv;
        }
    }
}

extern "C" void kernel_launch(void* const* d_in, const int* in_sizes, int n_in,
                              void* d_out, int out_size, void* d_ws, size_t ws_size,
                              hipStream_t stream) {
    const float* x       = (const float*)d_in[0];
    const float* wmean   = (const float*)d_in[1];
    const float* wlogvar = (const float*)d_in[2];
    const float* bias    = (const float*)d_in[3];
    const float* noise   = (const float*)d_in[4];
    float* out           = (float*)d_out;

    const size_t sig_bytes = (size_t)O_ * I_ * 4;   // 4 MiB

    if (ws_size >= sig_bytes) {
        float* sigma = (float*)d_ws;
        gen_sigma<<<dim3(O_ * I_ / 4 / 256), dim3(256), 0, stream>>>(wlogvar, sigma);
        fused_gemm<true><<<dim3(1024), dim3(256), 0, stream>>>(
            x, wmean, sigma, bias, noise, out);
    } else {
        fused_gemm<false><<<dim3(1024), dim3(256), 0, stream>>>(
            x, wmean, wlogvar, bias, noise, out);
    }
}

// Round 4
// 130.162 us; speedup vs baseline: 1.1698x; 1.1698x over previous
//
#include <hip/hip_runtime.h>
#include <hip/hip_bf16.h>
#include <stdint.h>

// Problem constants
#define B_ 32
#define L_ 512
#define I_ 1024
#define O_ 1024
#define NSTEP (I_ / 32)   // 32 K-steps of BK=32

typedef float  f32x4  __attribute__((ext_vector_type(4)));
typedef __bf16 bf16x4 __attribute__((ext_vector_type(4)));
typedef __bf16 bf16x8 __attribute__((ext_vector_type(8)));

// ---- async global->LDS, 16B per lane (global_load_lds_dwordx4) ----
__device__ __forceinline__ void gload_lds16(const void* g, void* l) {
    __builtin_amdgcn_global_load_lds(
        (const __attribute__((address_space(1))) uint32_t*)(uintptr_t)g,
        (__attribute__((address_space(3))) uint32_t*)(uint32_t)(uintptr_t)l,
        16, 0, 0);
}

// ============================ Pass 1: W = mean + eps*exp(0.5*lv) (bf16)  +  x -> bf16 ============================
// Single grid-stride kernel over both jobs: keeps HBM saturated, one launch.
__global__ __launch_bounds__(256) void prep_kernel(
    const float* __restrict__ x, const float* __restrict__ wmean,
    const float* __restrict__ wlv, const float* __restrict__ noise,
    __bf16* __restrict__ W, __bf16* __restrict__ xb)
{
    const int NW4 = B_ * O_ * I_ / 4;          // 8388608 W groups
    const int NX4 = B_ * L_ * I_ / 4;          // 4194304 x groups
    const int total = NW4 + NX4;
    const int stride = gridDim.x * blockDim.x;
    for (int i = blockIdx.x * blockDim.x + threadIdx.x; i < total; i += stride) {
        if (i < NW4) {
            const int mi = i & (O_ * I_ / 4 - 1);   // (O,I) index, reused per batch (L2/L3-hot)
            const f32x4 m4 = *(const f32x4*)(wmean + (size_t)mi * 4);
            const f32x4 l4 = *(const f32x4*)(wlv   + (size_t)mi * 4);
            const f32x4 e4 = *(const f32x4*)(noise + (size_t)i  * 4);
            bf16x4 w;
            w[0] = (__bf16)(m4[0] + e4[0] * __expf(0.5f * l4[0]));
            w[1] = (__bf16)(m4[1] + e4[1] * __expf(0.5f * l4[1]));
            w[2] = (__bf16)(m4[2] + e4[2] * __expf(0.5f * l4[2]));
            w[3] = (__bf16)(m4[3] + e4[3] * __expf(0.5f * l4[3]));
            *(bf16x4*)(W + (size_t)i * 4) = w;
        } else {
            const int j = i - NW4;
            const f32x4 v = *(const f32x4*)(x + (size_t)j * 4);
            bf16x4 w;
            w[0] = (__bf16)v[0]; w[1] = (__bf16)v[1];
            w[2] = (__bf16)v[2]; w[3] = (__bf16)v[3];
            *(bf16x4*)(xb + (size_t)j * 4) = w;
        }
    }
}

// ============================ Pass 2: bf16 GEMM, 2-phase double-buffered ============================
// C[b](512x1024) = Xb * W[b]^T + bias. 128x128 tile, BK=32, 4 waves (2x2, 64x64).
// T3 minimum-2-phase: STAGE(t+1 -> buf^1) issued BEFORE ds_read+MFMA(buf),
// one vmcnt(0)+barrier per K-step (inside __syncthreads).
__global__ __launch_bounds__(256) void gemm_2ph(const __bf16* __restrict__ xb,
                                                const __bf16* __restrict__ W,
                                                const float* __restrict__ bias,
                                                float* __restrict__ out)
{
    __shared__ __bf16 As[2][128 * 32];   // 8 KB per buf
    __shared__ __bf16 Bs[2][128 * 32];   // total 32 KB

    // bijective XCD swizzle (1024 % 8 == 0): 128 consecutive logical blocks per XCD.
    // Logical order: batch-major, mt outer, nt inner (8 nt-blocks share an x panel).
    const int bid = ((int)blockIdx.x & 7) * 128 + ((int)blockIdx.x >> 3);
    const int b   = bid >> 5;
    const int mt  = (bid >> 3) & 3;
    const int nt  = bid & 7;

    const int t    = threadIdx.x;
    const int wave = t >> 6, lane = t & 63;
    const int wr   = wave >> 1, wc = wave & 1;
    const int hr   = lane & 15, kq = lane >> 4;

    const __bf16* xrow = xb + (size_t)b * L_ * I_ + (size_t)(mt * 128) * I_;
    const __bf16* wrow = W  + (size_t)b * O_ * I_ + (size_t)(nt * 128) * I_;

    // staging: chunk t -> row t>>2, 8-elem col group t&3; chunk t+256 -> row+64.
    const int r1 = t >> 2, q1 = t & 3;
    const size_t goff1 = (size_t)r1 * I_ + q1 * 8;
    const size_t goff2 = (size_t)(r1 + 64) * I_ + q1 * 8;

    f32x4 acc[4][4];
    #pragma unroll
    for (int m = 0; m < 4; ++m)
        #pragma unroll
        for (int n = 0; n < 4; ++n)
            acc[m][n] = (f32x4)(0.0f);

    // prologue: stage K-tile 0 into buf 0
    gload_lds16(xrow + goff1, &As[0][t * 8]);
    gload_lds16(wrow + goff1, &Bs[0][t * 8]);
    gload_lds16(xrow + goff2, &As[0][t * 8 + 2048]);
    gload_lds16(wrow + goff2, &Bs[0][t * 8 + 2048]);
    __syncthreads();

    int cur = 0;
    for (int it = 0; it < NSTEP; ++it) {
        // (1) issue next K-tile's staging into the other buffer (overlaps with ds_read+MFMA)
        if (it + 1 < NSTEP) {
            const int k0n = (it + 1) * 32;
            const int nxt = cur ^ 1;
            gload_lds16(xrow + goff1 + k0n, &As[nxt][t * 8]);
            gload_lds16(wrow + goff1 + k0n, &Bs[nxt][t * 8]);
            gload_lds16(xrow + goff2 + k0n, &As[nxt][t * 8 + 2048]);
            gload_lds16(wrow + goff2 + k0n, &Bs[nxt][t * 8 + 2048]);
        }

        // (2) LDS -> frags -> MFMA on current buffer
        bf16x8 af[4], bfr[4];
        #pragma unroll
        for (int m = 0; m < 4; ++m)
            af[m] = *(const bf16x8*)&As[cur][(wr * 64 + m * 16 + hr) * 32 + kq * 8];
        #pragma unroll
        for (int n = 0; n < 4; ++n)
            bfr[n] = *(const bf16x8*)&Bs[cur][(wc * 64 + n * 16 + hr) * 32 + kq * 8];
        #pragma unroll
        for (int m = 0; m < 4; ++m)
            #pragma unroll
            for (int n = 0; n < 4; ++n)
                acc[m][n] = __builtin_amdgcn_mfma_f32_16x16x32_bf16(af[m], bfr[n], acc[m][n], 0, 0, 0);

        // (3) one barrier per K-step: drains vmcnt (next buffer ready), protects nothing
        //     else — the staged writes went to buf^1 only.
        __syncthreads();
        cur ^= 1;
    }

    // epilogue (validated R1-R3): C/D layout col=lane&15, row=(lane>>4)*4+reg
    float* ob = out + (size_t)b * L_ * O_;
    #pragma unroll
    for (int n = 0; n < 4; ++n) {
        const int col = nt * 128 + wc * 64 + n * 16 + hr;
        const float bv = bias[col];
        #pragma unroll
        for (int m = 0; m < 4; ++m) {
            const int row0 = mt * 128 + wr * 64 + m * 16 + kq * 4;
            #pragma unroll
            for (int j = 0; j < 4; ++j)
                ob[(size_t)(row0 + j) * O_ + col] = acc[m][n][j] + bv;
        }
    }
}

// ============================ Fallback (no workspace): R1 fused kernel ============================
#define LDSPAD 40
__global__ void bayes_gemm_fused(const float* __restrict__ x,
                                 const float* __restrict__ wmean,
                                 const float* __restrict__ wlogvar,
                                 const float* __restrict__ bias,
                                 const float* __restrict__ noise,
                                 float* __restrict__ out)
{
    __shared__ __bf16 As[128 * LDSPAD];
    __shared__ __bf16 Bs[128 * LDSPAD];
    const int bid  = blockIdx.x;
    const int b    = bid >> 5;
    const int mt   = (bid >> 3) & 3;
    const int nt   = bid & 7;
    const int t    = threadIdx.x;
    const int wave = t >> 6, lane = t & 63;
    const int wr   = wave >> 1, wc = wave & 1;
    const int hr   = lane & 15, kq = lane >> 4;
    const float* xb = x     + (size_t)b * L_ * I_;
    const float* nb = noise + (size_t)b * O_ * I_;
    f32x4 acc[4][4];
    #pragma unroll
    for (int m = 0; m < 4; ++m)
        #pragma unroll
        for (int n = 0; n < 4; ++n) acc[m][n] = (f32x4)(0.0f);
    for (int k0 = 0; k0 < I_; k0 += 32) {
        #pragma unroll
        for (int j = 0; j < 4; ++j) {
            const int s = t + j * 256, row = s >> 3, q = s & 7;
            const float4 v = *(const float4*)(xb + (size_t)(mt * 128 + row) * I_ + k0 + q * 4);
            __bf16* dst = &As[row * LDSPAD + q * 4];
            dst[0] = (__bf16)v.x; dst[1] = (__bf16)v.y; dst[2] = (__bf16)v.z; dst[3] = (__bf16)v.w;
        }
        #pragma unroll
        for (int j = 0; j < 4; ++j) {
            const int s = t + j * 256, row = s >> 3, q = s & 7;
            const size_t off = (size_t)(nt * 128 + row) * I_ + k0 + q * 4;
            const float4 m4 = *(const float4*)(wmean + off);
            const float4 l4 = *(const float4*)(wlogvar + off);
            const float4 n4 = *(const float4*)(nb + off);
            __bf16* dst = &Bs[row * LDSPAD + q * 4];
            dst[0] = (__bf16)(m4.x + n4.x * __expf(0.5f * l4.x));
            dst[1] = (__bf16)(m4.y + n4.y * __expf(0.5f * l4.y));
            dst[2] = (__bf16)(m4.z + n4.z * __expf(0.5f * l4.z));
            dst[3] = (__bf16)(m4.w + n4.w * __expf(0.5f * l4.w));
        }
        __syncthreads();
        bf16x8 af[4], bfr[4];
        #pragma unroll
        for (int m = 0; m < 4; ++m)
            af[m] = *(const bf16x8*)&As[(wr * 64 + m * 16 + hr) * LDSPAD + kq * 8];
        #pragma unroll
        for (int n = 0; n < 4; ++n)
            bfr[n] = *(const bf16x8*)&Bs[(wc * 64 + n * 16 + hr) * LDSPAD + kq * 8];
        #pragma unroll
        for (int m = 0; m < 4; ++m)
            #pragma unroll
            for (int n = 0; n < 4; ++n)
                acc[m][n] = __builtin_amdgcn_mfma_f32_16x16x32_bf16(af[m], bfr[n], acc[m][n], 0, 0, 0);
        __syncthreads();
    }
    float* ob = out + (size_t)b * L_ * O_;
    #pragma unroll
    for (int n = 0; n < 4; ++n) {
        const int col = nt * 128 + wc * 64 + n * 16 + hr;
        const float bv = bias[col];
        #pragma unroll
        for (int m = 0; m < 4; ++m) {
            const int row0 = mt * 128 + wr * 64 + m * 16 + kq * 4;
            #pragma unroll
            for (int j = 0; j < 4; ++j)
                ob[(size_t)(row0 + j) * O_ + col] = acc[m][n][j] + bv;
        }
    }
}

extern "C" void kernel_launch(void* const* d_in, const int* in_sizes, int n_in,
                              void* d_out, int out_size, void* d_ws, size_t ws_size,
                              hipStream_t stream) {
    const float* x       = (const float*)d_in[0];
    const float* wmean   = (const float*)d_in[1];
    const float* wlogvar = (const float*)d_in[2];
    const float* bias    = (const float*)d_in[3];
    const float* noise   = (const float*)d_in[4];
    float* out           = (float*)d_out;

    const size_t w_bytes  = (size_t)B_ * O_ * I_ * 2;   // 64 MiB
    const size_t xb_bytes = (size_t)B_ * L_ * I_ * 2;   // 32 MiB

    if (ws_size >= w_bytes + xb_bytes) {
        __bf16* W  = (__bf16*)d_ws;
        __bf16* xb = (__bf16*)((char*)d_ws + w_bytes);
        prep_kernel<<<dim3(2048), dim3(256), 0, stream>>>(x, wmean, wlogvar, noise, W, xb);
        gemm_2ph<<<dim3(1024), dim3(256), 0, stream>>>(xb, W, bias, out);
    } else {
        bayes_gemm_fused<<<dim3(1024), dim3(256), 0, stream>>>(
            x, wmean, wlogvar, bias, noise, out);
    }
}

// Round 5
// 124.585 us; speedup vs baseline: 1.2222x; 1.0448x over previous
//
#include <hip/hip_runtime.h>
#include <hip/hip_bf16.h>
#include <stdint.h>

// Problem constants
#define B_ 32
#define L_ 512
#define I_ 1024
#define O_ 1024
#define NSTEP (I_ / 32)   // 32 K-steps of BK=32

typedef float  f32x4  __attribute__((ext_vector_type(4)));
typedef __bf16 bf16x4 __attribute__((ext_vector_type(4)));
typedef __bf16 bf16x8 __attribute__((ext_vector_type(8)));

// ---- async global->LDS, 16B per lane (global_load_lds_dwordx4) ----
__device__ __forceinline__ void gload_lds16(const void* g, void* l) {
    __builtin_amdgcn_global_load_lds(
        (const __attribute__((address_space(1))) uint32_t*)(uintptr_t)g,
        (__attribute__((address_space(3))) uint32_t*)(uint32_t)(uintptr_t)l,
        16, 0, 0);
}

// ============================ Pass 1a: W = mean + eps * exp(0.5*lv) ============================
// Branchless grid-stride loop (R2-proven ~6.2 TB/s — do NOT merge with cvt_x:
// the R4 merged version's per-iteration branch killed load pipelining, 2.2 TB/s).
__global__ void gen_w_kernel(const float* __restrict__ wmean,
                             const float* __restrict__ wlv,
                             const float* __restrict__ noise,
                             __bf16* __restrict__ W)
{
    const int n4 = B_ * O_ * I_ / 4;          // 8388608 float4 groups
    const int stride = gridDim.x * blockDim.x;
    for (int i = blockIdx.x * blockDim.x + threadIdx.x; i < n4; i += stride) {
        const int mi = i & (O_ * I_ / 4 - 1); // (O,I) index, reused per batch (L2/L3-hot)
        const f32x4 m4 = *(const f32x4*)(wmean + (size_t)mi * 4);
        const f32x4 l4 = *(const f32x4*)(wlv   + (size_t)mi * 4);
        const f32x4 e4 = *(const f32x4*)(noise + (size_t)i  * 4);
        bf16x4 w;
        w[0] = (__bf16)(m4[0] + e4[0] * __expf(0.5f * l4[0]));
        w[1] = (__bf16)(m4[1] + e4[1] * __expf(0.5f * l4[1]));
        w[2] = (__bf16)(m4[2] + e4[2] * __expf(0.5f * l4[2]));
        w[3] = (__bf16)(m4[3] + e4[3] * __expf(0.5f * l4[3]));
        *(bf16x4*)(W + (size_t)i * 4) = w;
    }
}

// ============================ Pass 1b: x -> bf16 ============================
__global__ void cvt_x_kernel(const float* __restrict__ x, __bf16* __restrict__ xb)
{
    const int n4 = B_ * L_ * I_ / 4;          // 4194304
    const int stride = gridDim.x * blockDim.x;
    for (int i = blockIdx.x * blockDim.x + threadIdx.x; i < n4; i += stride) {
        const f32x4 v = *(const f32x4*)(x + (size_t)i * 4);
        bf16x4 w;
        w[0] = (__bf16)v[0]; w[1] = (__bf16)v[1];
        w[2] = (__bf16)v[2]; w[3] = (__bf16)v[3];
        *(bf16x4*)(xb + (size_t)i * 4) = w;
    }
}

// ============================ Pass 2: bf16 GEMM, 2-phase double-buffered ============================
// (R4-proven ~35 us, ~980 TF) C[b](512x1024) = Xb * W[b]^T + bias.
// 128x128 tile, BK=32, 4 waves (2x2, 64x64). STAGE(t+1 -> buf^1) issued BEFORE
// ds_read+MFMA(buf), ONE vmcnt-draining barrier per K-step.
__global__ __launch_bounds__(256) void gemm_2ph(const __bf16* __restrict__ xb,
                                                const __bf16* __restrict__ W,
                                                const float* __restrict__ bias,
                                                float* __restrict__ out)
{
    __shared__ __bf16 As[2][128 * 32];   // 8 KB per buf
    __shared__ __bf16 Bs[2][128 * 32];   // total 32 KB

    // bijective XCD swizzle (1024 % 8 == 0): 128 consecutive logical blocks per XCD.
    const int bid = ((int)blockIdx.x & 7) * 128 + ((int)blockIdx.x >> 3);
    const int b   = bid >> 5;
    const int mt  = (bid >> 3) & 3;
    const int nt  = bid & 7;

    const int t    = threadIdx.x;
    const int wave = t >> 6, lane = t & 63;
    const int wr   = wave >> 1, wc = wave & 1;
    const int hr   = lane & 15, kq = lane >> 4;

    const __bf16* xrow = xb + (size_t)b * L_ * I_ + (size_t)(mt * 128) * I_;
    const __bf16* wrow = W  + (size_t)b * O_ * I_ + (size_t)(nt * 128) * I_;

    const int r1 = t >> 2, q1 = t & 3;
    const size_t goff1 = (size_t)r1 * I_ + q1 * 8;
    const size_t goff2 = (size_t)(r1 + 64) * I_ + q1 * 8;

    f32x4 acc[4][4];
    #pragma unroll
    for (int m = 0; m < 4; ++m)
        #pragma unroll
        for (int n = 0; n < 4; ++n)
            acc[m][n] = (f32x4)(0.0f);

    // prologue: stage K-tile 0 into buf 0
    gload_lds16(xrow + goff1, &As[0][t * 8]);
    gload_lds16(wrow + goff1, &Bs[0][t * 8]);
    gload_lds16(xrow + goff2, &As[0][t * 8 + 2048]);
    gload_lds16(wrow + goff2, &Bs[0][t * 8 + 2048]);
    __syncthreads();

    int cur = 0;
    for (int it = 0; it < NSTEP; ++it) {
        if (it + 1 < NSTEP) {
            const int k0n = (it + 1) * 32;
            const int nxt = cur ^ 1;
            gload_lds16(xrow + goff1 + k0n, &As[nxt][t * 8]);
            gload_lds16(wrow + goff1 + k0n, &Bs[nxt][t * 8]);
            gload_lds16(xrow + goff2 + k0n, &As[nxt][t * 8 + 2048]);
            gload_lds16(wrow + goff2 + k0n, &Bs[nxt][t * 8 + 2048]);
        }

        bf16x8 af[4], bfr[4];
        #pragma unroll
        for (int m = 0; m < 4; ++m)
            af[m] = *(const bf16x8*)&As[cur][(wr * 64 + m * 16 + hr) * 32 + kq * 8];
        #pragma unroll
        for (int n = 0; n < 4; ++n)
            bfr[n] = *(const bf16x8*)&Bs[cur][(wc * 64 + n * 16 + hr) * 32 + kq * 8];
        #pragma unroll
        for (int m = 0; m < 4; ++m)
            #pragma unroll
            for (int n = 0; n < 4; ++n)
                acc[m][n] = __builtin_amdgcn_mfma_f32_16x16x32_bf16(af[m], bfr[n], acc[m][n], 0, 0, 0);

        __syncthreads();
        cur ^= 1;
    }

    // epilogue (validated R1-R4): C/D layout col=lane&15, row=(lane>>4)*4+reg
    float* ob = out + (size_t)b * L_ * O_;
    #pragma unroll
    for (int n = 0; n < 4; ++n) {
        const int col = nt * 128 + wc * 64 + n * 16 + hr;
        const float bv = bias[col];
        #pragma unroll
        for (int m = 0; m < 4; ++m) {
            const int row0 = mt * 128 + wr * 64 + m * 16 + kq * 4;
            #pragma unroll
            for (int j = 0; j < 4; ++j)
                ob[(size_t)(row0 + j) * O_ + col] = acc[m][n][j] + bv;
        }
    }
}

// ============================ Fallback (no workspace): R1 fused kernel ============================
#define LDSPAD 40
__global__ void bayes_gemm_fused(const float* __restrict__ x,
                                 const float* __restrict__ wmean,
                                 const float* __restrict__ wlogvar,
                                 const float* __restrict__ bias,
                                 const float* __restrict__ noise,
                                 float* __restrict__ out)
{
    __shared__ __bf16 As[128 * LDSPAD];
    __shared__ __bf16 Bs[128 * LDSPAD];
    const int bid  = blockIdx.x;
    const int b    = bid >> 5;
    const int mt   = (bid >> 3) & 3;
    const int nt   = bid & 7;
    const int t    = threadIdx.x;
    const int wave = t >> 6, lane = t & 63;
    const int wr   = wave >> 1, wc = wave & 1;
    const int hr   = lane & 15, kq = lane >> 4;
    const float* xb = x     + (size_t)b * L_ * I_;
    const float* nb = noise + (size_t)b * O_ * I_;
    f32x4 acc[4][4];
    #pragma unroll
    for (int m = 0; m < 4; ++m)
        #pragma unroll
        for (int n = 0; n < 4; ++n) acc[m][n] = (f32x4)(0.0f);
    for (int k0 = 0; k0 < I_; k0 += 32) {
        #pragma unroll
        for (int j = 0; j < 4; ++j) {
            const int s = t + j * 256, row = s >> 3, q = s & 7;
            const float4 v = *(const float4*)(xb + (size_t)(mt * 128 + row) * I_ + k0 + q * 4);
            __bf16* dst = &As[row * LDSPAD + q * 4];
            dst[0] = (__bf16)v.x; dst[1] = (__bf16)v.y; dst[2] = (__bf16)v.z; dst[3] = (__bf16)v.w;
        }
        #pragma unroll
        for (int j = 0; j < 4; ++j) {
            const int s = t + j * 256, row = s >> 3, q = s & 7;
            const size_t off = (size_t)(nt * 128 + row) * I_ + k0 + q * 4;
            const float4 m4 = *(const float4*)(wmean + off);
            const float4 l4 = *(const float4*)(wlogvar + off);
            const float4 n4 = *(const float4*)(nb + off);
            __bf16* dst = &Bs[row * LDSPAD + q * 4];
            dst[0] = (__bf16)(m4.x + n4.x * __expf(0.5f * l4.x));
            dst[1] = (__bf16)(m4.y + n4.y * __expf(0.5f * l4.y));
            dst[2] = (__bf16)(m4.z + n4.z * __expf(0.5f * l4.z));
            dst[3] = (__bf16)(m4.w + n4.w * __expf(0.5f * l4.w));
        }
        __syncthreads();
        bf16x8 af[4], bfr[4];
        #pragma unroll
        for (int m = 0; m < 4; ++m)
            af[m] = *(const bf16x8*)&As[(wr * 64 + m * 16 + hr) * LDSPAD + kq * 8];
        #pragma unroll
        for (int n = 0; n < 4; ++n)
            bfr[n] = *(const bf16x8*)&Bs[(wc * 64 + n * 16 + hr) * LDSPAD + kq * 8];
        #pragma unroll
        for (int m = 0; m < 4; ++m)
            #pragma unroll
            for (int n = 0; n < 4; ++n)
                acc[m][n] = __builtin_amdgcn_mfma_f32_16x16x32_bf16(af[m], bfr[n], acc[m][n], 0, 0, 0);
        __syncthreads();
    }
    float* ob = out + (size_t)b * L_ * O_;
    #pragma unroll
    for (int n = 0; n < 4; ++n) {
        const int col = nt * 128 + wc * 64 + n * 16 + hr;
        const float bv = bias[col];
        #pragma unroll
        for (int m = 0; m < 4; ++m) {
            const int row0 = mt * 128 + wr * 64 + m * 16 + kq * 4;
            #pragma unroll
            for (int j = 0; j < 4; ++j)
                ob[(size_t)(row0 + j) * O_ + col] = acc[m][n][j] + bv;
        }
    }
}

extern "C" void kernel_launch(void* const* d_in, const int* in_sizes, int n_in,
                              void* d_out, int out_size, void* d_ws, size_t ws_size,
                              hipStream_t stream) {
    const float* x       = (const float*)d_in[0];
    const float* wmean   = (const float*)d_in[1];
    const float* wlogvar = (const float*)d_in[2];
    const float* bias    = (const float*)d_in[3];
    const float* noise   = (const float*)d_in[4];
    float* out           = (float*)d_out;

    const size_t w_bytes  = (size_t)B_ * O_ * I_ * 2;   // 64 MiB
    const size_t xb_bytes = (size_t)B_ * L_ * I_ * 2;   // 32 MiB

    if (ws_size >= w_bytes + xb_bytes) {
        __bf16* W  = (__bf16*)d_ws;
        __bf16* xb = (__bf16*)((char*)d_ws + w_bytes);
        gen_w_kernel<<<dim3(2048), dim3(256), 0, stream>>>(wmean, wlogvar, noise, W);
        cvt_x_kernel<<<dim3(1024), dim3(256), 0, stream>>>(x, xb);
        gemm_2ph<<<dim3(1024), dim3(256), 0, stream>>>(xb, W, bias, out);
    } else {
        bayes_gemm_fused<<<dim3(1024), dim3(256), 0, stream>>>(
            x, wmean, wlogvar, bias, noise, out);
    }
}

// Round 6
// 113.752 us; speedup vs baseline: 1.3386x; 1.0952x over previous
//
#include <hip/hip_runtime.h>
#include <hip/hip_bf16.h>
#include <stdint.h>

// Problem constants
#define B_ 32
#define L_ 512
#define I_ 1024
#define O_ 1024
#define BK 32
#define NT (I_ / BK)      // 32 K-tiles

typedef float  f32x4  __attribute__((ext_vector_type(4)));
typedef __bf16 bf16x4 __attribute__((ext_vector_type(4)));
typedef __bf16 bf16x8 __attribute__((ext_vector_type(8)));

// ---- async global->LDS, 16B per lane (global_load_lds_dwordx4) ----
__device__ __forceinline__ void gload_lds16(const void* g, void* l) {
    __builtin_amdgcn_global_load_lds(
        (const __attribute__((address_space(1))) uint32_t*)(uintptr_t)g,
        (__attribute__((address_space(3))) uint32_t*)(uint32_t)(uintptr_t)l,
        16, 0, 0);
}

// ============================ Pass 1a: W = mean + eps * exp(0.5*lv) ============================
// Branchless grid-stride (R2/R5-proven ~6.2 TB/s). Do NOT merge with cvt_x (R4 regression).
__global__ void gen_w_kernel(const float* __restrict__ wmean,
                             const float* __restrict__ wlv,
                             const float* __restrict__ noise,
                             __bf16* __restrict__ W)
{
    const int n4 = B_ * O_ * I_ / 4;
    const int stride = gridDim.x * blockDim.x;
    for (int i = blockIdx.x * blockDim.x + threadIdx.x; i < n4; i += stride) {
        const int mi = i & (O_ * I_ / 4 - 1);
        const f32x4 m4 = *(const f32x4*)(wmean + (size_t)mi * 4);
        const f32x4 l4 = *(const f32x4*)(wlv   + (size_t)mi * 4);
        const f32x4 e4 = *(const f32x4*)(noise + (size_t)i  * 4);
        bf16x4 w;
        w[0] = (__bf16)(m4[0] + e4[0] * __expf(0.5f * l4[0]));
        w[1] = (__bf16)(m4[1] + e4[1] * __expf(0.5f * l4[1]));
        w[2] = (__bf16)(m4[2] + e4[2] * __expf(0.5f * l4[2]));
        w[3] = (__bf16)(m4[3] + e4[3] * __expf(0.5f * l4[3]));
        *(bf16x4*)(W + (size_t)i * 4) = w;
    }
}

// ============================ Pass 1b: x -> bf16 ============================
__global__ void cvt_x_kernel(const float* __restrict__ x, __bf16* __restrict__ xb)
{
    const int n4 = B_ * L_ * I_ / 4;
    const int stride = gridDim.x * blockDim.x;
    for (int i = blockIdx.x * blockDim.x + threadIdx.x; i < n4; i += stride) {
        const f32x4 v = *(const f32x4*)(x + (size_t)i * 4);
        bf16x4 w;
        w[0] = (__bf16)v[0]; w[1] = (__bf16)v[1];
        w[2] = (__bf16)v[2]; w[3] = (__bf16)v[3];
        *(bf16x4*)(xb + (size_t)i * 4) = w;
    }
}

// ============================ Pass 2: 256x256 8-wave GEMM, 4-deep counted-vmcnt ring ============================
// C[b](512x1024) = Xb * W[b]^T + bias.  BM=BN=256, BK=32, 512 thr = 8 waves (2x4),
// per-wave 128x64 out = 8x4 frags of 16x16x32.  LDS ring: 4 bufs x (A 16KB + B 16KB) = 128 KB.
// Pipeline: prefetch depth 3; per K-step {vmcnt(8) counted -> s_barrier -> stage(t+3)
// -> 12 ds_read_b128 -> setprio(1) 32 MFMA setprio(0)}. ONE barrier/step; vmcnt never
// drains to 0 in the main loop (T4). Tail drains 8->4->0.
// Bank-conflict fix (rule #21 compliant, no ds_write): involution swizzle
// chunk' = chunk ^ ((row>>1)&3) applied to the GLOBAL source address at stage time
// and to the ds_read address; LDS dest stays linear (gload_lds requirement).
__global__ __launch_bounds__(512, 2) void gemm_ring(const __bf16* __restrict__ xb,
                                                    const __bf16* __restrict__ W,
                                                    const float* __restrict__ bias,
                                                    float* __restrict__ out)
{
    __shared__ __bf16 Abuf[4][256 * BK];   // 16 KB per buf
    __shared__ __bf16 Bbuf[4][256 * BK];   // total 128 KB

    // 256 blocks, XCD swizzle (256%8==0): each XCD gets 32 consecutive logical
    // blocks = 4 whole batches (8 blocks/batch: 2 mt x 4 nt) -> W/x reuse in private L2.
    const int bid = ((int)blockIdx.x & 7) * 32 + ((int)blockIdx.x >> 3);
    const int b   = bid >> 3;          // batch
    const int mt  = (bid >> 2) & 1;    // 2 M-tiles of 256
    const int nt  = bid & 3;           // 4 N-tiles of 256

    const int tid  = threadIdx.x;      // 0..511
    const int wid  = tid >> 6, lane = tid & 63;
    const int wr   = wid >> 2;         // 0..1  (M)
    const int wc   = wid & 3;          // 0..3  (N)
    const int hr   = lane & 15;
    const int kq   = lane >> 4;        // 0..3

    // ---- staging geometry: thread covers phys 16B-chunks tid and tid+512 ----
    // phys chunk p -> row p>>2, pchunk p&3; logical col-chunk = pchunk ^ ((row>>1)&3)
    const int rowS = tid >> 2;                       // 0..127 (second slot: +128)
    const int pcS  = tid & 3;
    const int cS   = pcS ^ ((rowS >> 1) & 3);        // same for row+128
    const __bf16* ga = xb + (size_t)b * L_ * I_ + (size_t)(mt * 256 + rowS) * I_ + cS * 8;
    const __bf16* gb = W  + (size_t)b * O_ * I_ + (size_t)(nt * 256 + rowS) * I_ + cS * 8;
    const size_t ghalf = (size_t)128 * I_;           // +128 rows

#define STAGE(kt_) {                                                        \
        const int bsel_ = (kt_) & 3;                                        \
        const int ko_   = (kt_) * BK;                                       \
        gload_lds16(ga + ko_,         &Abuf[bsel_][tid * 8]);               \
        gload_lds16(ga + ko_ + ghalf, &Abuf[bsel_][tid * 8 + 4096]);        \
        gload_lds16(gb + ko_,         &Bbuf[bsel_][tid * 8]);               \
        gload_lds16(gb + ko_ + ghalf, &Bbuf[bsel_][tid * 8 + 4096]);        \
    }

    // ---- ds_read offsets (bytes), with the same involution on the read side ----
    const int xorv = (hr >> 1) & 3;
    const int pch  = kq ^ xorv;
    const int aoff = (wr * 128 + hr) * 64 + pch * 16;   // + m*1024
    const int boff = (wc * 64  + hr) * 64 + pch * 16;   // + n*1024

    f32x4 acc[8][4];
    #pragma unroll
    for (int m = 0; m < 8; ++m)
        #pragma unroll
        for (int n = 0; n < 4; ++n)
            acc[m][n] = (f32x4)(0.0f);

    // prologue: fill pipeline 3 deep (12 loads/thread outstanding)
    STAGE(0); STAGE(1); STAGE(2);

    for (int kt = 0; kt < NT; ++kt) {
        // counted wait: oldest stage (tile kt) complete; tiles kt+1, kt+2 stay in flight
        if (kt <= NT - 3)      asm volatile("s_waitcnt vmcnt(8)" ::: "memory");
        else if (kt == NT - 2) asm volatile("s_waitcnt vmcnt(4)" ::: "memory");
        else                   asm volatile("s_waitcnt vmcnt(0)" ::: "memory");
        __builtin_amdgcn_s_barrier();      // all waves: tile kt fully in LDS
        asm volatile("" ::: "memory");

        // issue next prefetch into the freed ring slot (last read at iter kt-1, safe)
        if (kt + 3 < NT) STAGE(kt + 3);

        const char* As = (const char*)&Abuf[kt & 3][0];
        const char* Bs = (const char*)&Bbuf[kt & 3][0];

        bf16x8 af[8], bfr[4];
        #pragma unroll
        for (int m = 0; m < 8; ++m)
            af[m] = *(const bf16x8*)(As + aoff + m * 1024);
        #pragma unroll
        for (int n = 0; n < 4; ++n)
            bfr[n] = *(const bf16x8*)(Bs + boff + n * 1024);

        __builtin_amdgcn_s_setprio(1);
        #pragma unroll
        for (int m = 0; m < 8; ++m)
            #pragma unroll
            for (int n = 0; n < 4; ++n)
                acc[m][n] = __builtin_amdgcn_mfma_f32_16x16x32_bf16(af[m], bfr[n], acc[m][n], 0, 0, 0);
        __builtin_amdgcn_s_setprio(0);
        // no second barrier needed: next iter's barrier orders reads vs the next STAGE
    }
#undef STAGE

    // epilogue (validated R1-R5): C/D layout col=lane&15, row=(lane>>4)*4+reg
    float* ob = out + (size_t)b * L_ * O_;
    #pragma unroll
    for (int n = 0; n < 4; ++n) {
        const int col = nt * 256 + wc * 64 + n * 16 + hr;
        const float bv = bias[col];
        #pragma unroll
        for (int m = 0; m < 8; ++m) {
            const int row0 = mt * 256 + wr * 128 + m * 16 + kq * 4;
            #pragma unroll
            for (int j = 0; j < 4; ++j)
                ob[(size_t)(row0 + j) * O_ + col] = acc[m][n][j] + bv;
        }
    }
}

// ============================ Fallback (no workspace): R1 fused kernel ============================
#define LDSPAD 40
__global__ void bayes_gemm_fused(const float* __restrict__ x,
                                 const float* __restrict__ wmean,
                                 const float* __restrict__ wlogvar,
                                 const float* __restrict__ bias,
                                 const float* __restrict__ noise,
                                 float* __restrict__ out)
{
    __shared__ __bf16 As[128 * LDSPAD];
    __shared__ __bf16 Bs[128 * LDSPAD];
    const int bid  = blockIdx.x;
    const int b    = bid >> 5;
    const int mt   = (bid >> 3) & 3;
    const int nt   = bid & 7;
    const int t    = threadIdx.x;
    const int wave = t >> 6, lane = t & 63;
    const int wr   = wave >> 1, wc = wave & 1;
    const int hr   = lane & 15, kq = lane >> 4;
    const float* xb = x     + (size_t)b * L_ * I_;
    const float* nb = noise + (size_t)b * O_ * I_;
    f32x4 acc[4][4];
    #pragma unroll
    for (int m = 0; m < 4; ++m)
        #pragma unroll
        for (int n = 0; n < 4; ++n) acc[m][n] = (f32x4)(0.0f);
    for (int k0 = 0; k0 < I_; k0 += 32) {
        #pragma unroll
        for (int j = 0; j < 4; ++j) {
            const int s = t + j * 256, row = s >> 3, q = s & 7;
            const float4 v = *(const float4*)(xb + (size_t)(mt * 128 + row) * I_ + k0 + q * 4);
            __bf16* dst = &As[row * LDSPAD + q * 4];
            dst[0] = (__bf16)v.x; dst[1] = (__bf16)v.y; dst[2] = (__bf16)v.z; dst[3] = (__bf16)v.w;
        }
        #pragma unroll
        for (int j = 0; j < 4; ++j) {
            const int s = t + j * 256, row = s >> 3, q = s & 7;
            const size_t off = (size_t)(nt * 128 + row) * I_ + k0 + q * 4;
            const float4 m4 = *(const float4*)(wmean + off);
            const float4 l4 = *(const float4*)(wlogvar + off);
            const float4 n4 = *(const float4*)(nb + off);
            __bf16* dst = &Bs[row * LDSPAD + q * 4];
            dst[0] = (__bf16)(m4.x + n4.x * __expf(0.5f * l4.x));
            dst[1] = (__bf16)(m4.y + n4.y * __expf(0.5f * l4.y));
            dst[2] = (__bf16)(m4.z + n4.z * __expf(0.5f * l4.z));
            dst[3] = (__bf16)(m4.w + n4.w * __expf(0.5f * l4.w));
        }
        __syncthreads();
        bf16x8 af[4], bfr[4];
        #pragma unroll
        for (int m = 0; m < 4; ++m)
            af[m] = *(const bf16x8*)&As[(wr * 64 + m * 16 + hr) * LDSPAD + kq * 8];
        #pragma unroll
        for (int n = 0; n < 4; ++n)
            bfr[n] = *(const bf16x8*)&Bs[(wc * 64 + n * 16 + hr) * LDSPAD + kq * 8];
        #pragma unroll
        for (int m = 0; m < 4; ++m)
            #pragma unroll
            for (int n = 0; n < 4; ++n)
                acc[m][n] = __builtin_amdgcn_mfma_f32_16x16x32_bf16(af[m], bfr[n], acc[m][n], 0, 0, 0);
        __syncthreads();
    }
    float* ob = out + (size_t)b * L_ * O_;
    #pragma unroll
    for (int n = 0; n < 4; ++n) {
        const int col = nt * 128 + wc * 64 + n * 16 + hr;
        const float bv = bias[col];
        #pragma unroll
        for (int m = 0; m < 4; ++m) {
            const int row0 = mt * 128 + wr * 64 + m * 16 + kq * 4;
            #pragma unroll
            for (int j = 0; j < 4; ++j)
                ob[(size_t)(row0 + j) * O_ + col] = acc[m][n][j] + bv;
        }
    }
}

extern "C" void kernel_launch(void* const* d_in, const int* in_sizes, int n_in,
                              void* d_out, int out_size, void* d_ws, size_t ws_size,
                              hipStream_t stream) {
    const float* x       = (const float*)d_in[0];
    const float* wmean   = (const float*)d_in[1];
    const float* wlogvar = (const float*)d_in[2];
    const float* bias    = (const float*)d_in[3];
    const float* noise   = (const float*)d_in[4];
    float* out           = (float*)d_out;

    const size_t w_bytes  = (size_t)B_ * O_ * I_ * 2;   // 64 MiB
    const size_t xb_bytes = (size_t)B_ * L_ * I_ * 2;   // 32 MiB

    if (ws_size >= w_bytes + xb_bytes) {
        __bf16* W  = (__bf16*)d_ws;
        __bf16* xbuf = (__bf16*)((char*)d_ws + w_bytes);
        gen_w_kernel<<<dim3(2048), dim3(256), 0, stream>>>(wmean, wlogvar, noise, W);
        cvt_x_kernel<<<dim3(1024), dim3(256), 0, stream>>>(x, xbuf);
        gemm_ring<<<dim3(256), dim3(512), 0, stream>>>(xbuf, W, bias, out);
    } else {
        bayes_gemm_fused<<<dim3(1024), dim3(256), 0, stream>>>(
            x, wmean, wlogvar, bias, noise, out);
    }
}

// Round 8
// 110.337 us; speedup vs baseline: 1.3800x; 1.0310x over previous
//
#include <hip/hip_runtime.h>
#include <hip/hip_bf16.h>
#include <stdint.h>

// Problem constants
#define B_ 32
#define L_ 512
#define I_ 1024
#define O_ 1024
#define NKT 16            // K-tiles of BK=64

typedef float  f32x4  __attribute__((ext_vector_type(4)));
typedef __bf16 bf16x4 __attribute__((ext_vector_type(4)));
typedef __bf16 bf16x8 __attribute__((ext_vector_type(8)));

#define CFENCE() asm volatile("" ::: "memory")
#define BARRIER() do { CFENCE(); __builtin_amdgcn_s_barrier(); CFENCE(); } while (0)

// ---- async global->LDS, 16B per lane (global_load_lds_dwordx4) ----
__device__ __forceinline__ void gload_lds16(const void* g, void* l) {
    __builtin_amdgcn_global_load_lds(
        (const __attribute__((address_space(1))) uint32_t*)(uintptr_t)g,
        (__attribute__((address_space(3))) uint32_t*)(uint32_t)(uintptr_t)l,
        16, 0, 0);
}

// ============================ Pass 1a: W = mean + eps * exp(0.5*lv) ============================
// Branchless grid-stride (R2/R5-proven ~6.2 TB/s). Do NOT merge with cvt_x (R4 regression).
__global__ void gen_w_kernel(const float* __restrict__ wmean,
                             const float* __restrict__ wlv,
                             const float* __restrict__ noise,
                             __bf16* __restrict__ W)
{
    const int n4 = B_ * O_ * I_ / 4;
    const int stride = gridDim.x * blockDim.x;
    for (int i = blockIdx.x * blockDim.x + threadIdx.x; i < n4; i += stride) {
        const int mi = i & (O_ * I_ / 4 - 1);
        const f32x4 m4 = *(const f32x4*)(wmean + (size_t)mi * 4);
        const f32x4 l4 = *(const f32x4*)(wlv   + (size_t)mi * 4);
        const f32x4 e4 = *(const f32x4*)(noise + (size_t)i  * 4);
        bf16x4 w;
        w[0] = (__bf16)(m4[0] + e4[0] * __expf(0.5f * l4[0]));
        w[1] = (__bf16)(m4[1] + e4[1] * __expf(0.5f * l4[1]));
        w[2] = (__bf16)(m4[2] + e4[2] * __expf(0.5f * l4[2]));
        w[3] = (__bf16)(m4[3] + e4[3] * __expf(0.5f * l4[3]));
        *(bf16x4*)(W + (size_t)i * 4) = w;
    }
}

// ============================ Pass 1b: x -> bf16 ============================
__global__ void cvt_x_kernel(const float* __restrict__ x, __bf16* __restrict__ xb)
{
    const int n4 = B_ * L_ * I_ / 4;
    const int stride = gridDim.x * blockDim.x;
    for (int i = blockIdx.x * blockDim.x + threadIdx.x; i < n4; i += stride) {
        const f32x4 v = *(const f32x4*)(x + (size_t)i * 4);
        bf16x4 w;
        w[0] = (__bf16)v[0]; w[1] = (__bf16)v[1];
        w[2] = (__bf16)v[2]; w[3] = (__bf16)v[3];
        *(bf16x4*)(xb + (size_t)i * 4) = w;
    }
}

// ============================ Pass 2: 256x256 8-wave GEMM, m201 8-phase schedule ============================
// C[b](512x1024) = Xb * W[b]^T + bias.  BM=BN=256, BK=64, 512 thr = 8 waves (2M x 4N),
// per-wave 128x64 out = 8m x 4n frags.  LDS 128 KB: A[2dbuf][2half][128][64] + B same.
// Half-tile = 128 rows x 64 k = 16 KB = 2 gload_lds16/thread.
// Per K-tile t (4 phases, one barrier each):
//   P0: ds_read bfr(all 4n x 2kk) + af(m01) | stage Ah0(t+1) | 16 MFMA
//   P1: ds_read af(m23)                     | stage Ah1(t+1) | 16 MFMA
//   P2: ds_read af(m45)                     | stage Bh0(t+2) | 16 MFMA
//   P3: ds_read af(m67)                     | stage Bh1(t+2) | 16 MFMA | vmcnt(4)
// Counted vmcnt(4) once per tile (2 loads/half-tile x 2 half-tiles in flight); tail: vmcnt(0) at t=NKT-2.
// LDS swizzle: logical chunk c (16B) of row r stored at physical chunk c ^ (r&7)
// (involution; applied to GLOBAL src at stage time + ds_read addr; LDS dest linear).
// R7 bug (NaN): bob included the B-region base 65536 AND dB added it again ->
// B-frag reads landed past the 128 KB LDS allocation. Fixed: bob is region-relative.
__global__ __launch_bounds__(512, 2) void gemm_8ph(const __bf16* __restrict__ xb,
                                                   const __bf16* __restrict__ W,
                                                   const float* __restrict__ bias,
                                                   float* __restrict__ out)
{
    __shared__ __align__(16) char smem[131072];
    // A halftile slot (d,h): bytes (d*2+h)*16384 ; B halftile slot: 65536 + (d*2+h)*16384

    // 256 blocks, XCD swizzle (256%8==0): 32 consecutive logical blocks per XCD = 4 whole batches.
    const int bid = ((int)blockIdx.x & 7) * 32 + ((int)blockIdx.x >> 3);
    const int b   = bid >> 3;
    const int mt  = (bid >> 2) & 1;
    const int nt  = bid & 3;

    const int tid  = threadIdx.x;
    const int wid  = tid >> 6, lane = tid & 63;
    const int wr   = wid >> 2;         // 0..1 (M)
    const int wc   = wid & 3;          // 0..3 (N)
    const int hr   = lane & 15;
    const int kq   = lane >> 4;

    // ---- staging geometry: thread covers phys 16B chunks tid and tid+512 of a half-tile ----
    const int P0c = tid, P1c = tid + 512;
    const int r0 = P0c >> 3, c0 = (P0c & 7) ^ (r0 & 7);   // pre-swizzled global col chunk
    const int r1 = P1c >> 3, c1 = (P1c & 7) ^ (r1 & 7);
    const size_t gO0 = (size_t)r0 * I_ + c0 * 8;
    const size_t gO1 = (size_t)r1 * I_ + c1 * 8;

    const __bf16* ax = xb + (size_t)b * L_ * I_ + (size_t)(mt * 256) * I_;
    const __bf16* bw = W  + (size_t)b * O_ * I_ + (size_t)(nt * 256) * I_;

#define STG(srcp, slotbyte) do {                                          \
        gload_lds16((srcp) + gO0, smem + (slotbyte) + tid * 16);          \
        gload_lds16((srcp) + gO1, smem + (slotbyte) + 8192 + tid * 16);   \
    } while (0)

    // ---- ds_read fragment addressing (swizzled chunk) ----
    const int pc0 = (0 + kq) ^ (hr & 7);          // kk=0 chunk
    const int pc1 = (4 + kq) ^ (hr & 7);          // kk=1 chunk
    const int aob = wr * 16384 + hr * 128;                        // region-relative; + m*2048 + d*32768 + pc*16
    const int bob = (wc >> 1) * 16384 + (wc & 1) * 8192 + hr * 128;  // region-relative (FIX: no 65536 here)

    f32x4 acc[8][4];
    #pragma unroll
    for (int m = 0; m < 8; ++m)
        #pragma unroll
        for (int n = 0; n < 4; ++n)
            acc[m][n] = (f32x4)(0.0f);

#define LDA(mb, dA_) do {                                                             \
        _Pragma("unroll")                                                             \
        for (int mm = 0; mm < 2; ++mm) {                                              \
            af[mm][0] = *(const bf16x8*)(smem + (dA_) + aob + ((mb)+mm)*2048 + pc0*16); \
            af[mm][1] = *(const bf16x8*)(smem + (dA_) + aob + ((mb)+mm)*2048 + pc1*16); \
        } } while (0)

#define DO_MFMA(mb) do {                                                              \
        __builtin_amdgcn_s_setprio(1);                                                \
        _Pragma("unroll")                                                             \
        for (int mm = 0; mm < 2; ++mm)                                                \
            _Pragma("unroll")                                                         \
            for (int n = 0; n < 4; ++n)                                               \
                _Pragma("unroll")                                                     \
                for (int kk = 0; kk < 2; ++kk)                                        \
                    acc[(mb)+mm][n] = __builtin_amdgcn_mfma_f32_16x16x32_bf16(        \
                        af[mm][kk], bfr[n][kk], acc[(mb)+mm][n], 0, 0, 0);            \
        __builtin_amdgcn_s_setprio(0); } while (0)

    // ---- prologue: stage B(0), A(0), B(1); wait tile-0 resident (last 2 stages in flight) ----
    STG(bw,                         65536 + 0);
    STG(bw + (size_t)128 * I_,      65536 + 16384);
    STG(ax,                         0);
    STG(ax + (size_t)128 * I_,      16384);
    STG(bw + 64,                    65536 + 32768);
    STG(bw + (size_t)128 * I_ + 64, 65536 + 32768 + 16384);
    CFENCE(); asm volatile("s_waitcnt vmcnt(4)" ::: "memory");
    BARRIER();

    for (int t = 0; t < NKT; ++t) {
        const int d  = t & 1;
        const int dA = d * 32768;
        const int dB = 65536 + d * 32768;
        const int dN = (d ^ 1) * 32768;     // A dbuf for tile t+1
        bf16x8 af[2][2], bfr[4][2];

        // ---- P0: all B frags + A m01 ; stage Ah0(t+1) ----
        #pragma unroll
        for (int n = 0; n < 4; ++n) {
            bfr[n][0] = *(const bf16x8*)(smem + dB + bob + n * 2048 + pc0 * 16);
            bfr[n][1] = *(const bf16x8*)(smem + dB + bob + n * 2048 + pc1 * 16);
        }
        LDA(0, dA);
        if (t + 1 < NKT) STG(ax + (size_t)(t + 1) * 64, dN);
        DO_MFMA(0);
        BARRIER();

        // ---- P1: A m23 ; stage Ah1(t+1) ----
        LDA(2, dA);
        if (t + 1 < NKT) STG(ax + (size_t)128 * I_ + (size_t)(t + 1) * 64, dN + 16384);
        DO_MFMA(2);
        BARRIER();

        // ---- P2: A m45 ; stage Bh0(t+2) (tile t's B fully read at P0) ----
        LDA(4, dA);
        if (t + 2 < NKT) STG(bw + (size_t)(t + 2) * 64, dB);
        DO_MFMA(4);
        BARRIER();

        // ---- P3: A m67 ; stage Bh1(t+2) ; counted vmcnt at tile boundary ----
        LDA(6, dA);
        if (t + 2 < NKT) STG(bw + (size_t)128 * I_ + (size_t)(t + 2) * 64, dB + 16384);
        DO_MFMA(6);
        if (t < NKT - 2)       { CFENCE(); asm volatile("s_waitcnt vmcnt(4)" ::: "memory"); }
        else if (t == NKT - 2) { CFENCE(); asm volatile("s_waitcnt vmcnt(0)" ::: "memory"); }
        BARRIER();
    }
#undef STG
#undef LDA
#undef DO_MFMA

    // epilogue (validated R1-R6): C/D layout col=lane&15, row=(lane>>4)*4+reg
    float* ob = out + (size_t)b * L_ * O_;
    #pragma unroll
    for (int n = 0; n < 4; ++n) {
        const int col = nt * 256 + wc * 64 + n * 16 + hr;
        const float bv = bias[col];
        #pragma unroll
        for (int m = 0; m < 8; ++m) {
            const int row0 = mt * 256 + wr * 128 + m * 16 + kq * 4;
            #pragma unroll
            for (int j = 0; j < 4; ++j)
                ob[(size_t)(row0 + j) * O_ + col] = acc[m][n][j] + bv;
        }
    }
}

// ============================ Fallback (no workspace): R1 fused kernel ============================
#define LDSPAD 40
__global__ void bayes_gemm_fused(const float* __restrict__ x,
                                 const float* __restrict__ wmean,
                                 const float* __restrict__ wlogvar,
                                 const float* __restrict__ bias,
                                 const float* __restrict__ noise,
                                 float* __restrict__ out)
{
    __shared__ __bf16 As[128 * LDSPAD];
    __shared__ __bf16 Bs[128 * LDSPAD];
    const int bid  = blockIdx.x;
    const int b    = bid >> 5;
    const int mt   = (bid >> 3) & 3;
    const int nt   = bid & 7;
    const int t    = threadIdx.x;
    const int wave = t >> 6, lane = t & 63;
    const int wr   = wave >> 1, wc = wave & 1;
    const int hr   = lane & 15, kq = lane >> 4;
    const float* xb = x     + (size_t)b * L_ * I_;
    const float* nb = noise + (size_t)b * O_ * I_;
    f32x4 acc[4][4];
    #pragma unroll
    for (int m = 0; m < 4; ++m)
        #pragma unroll
        for (int n = 0; n < 4; ++n) acc[m][n] = (f32x4)(0.0f);
    for (int k0 = 0; k0 < I_; k0 += 32) {
        #pragma unroll
        for (int j = 0; j < 4; ++j) {
            const int s = t + j * 256, row = s >> 3, q = s & 7;
            const float4 v = *(const float4*)(xb + (size_t)(mt * 128 + row) * I_ + k0 + q * 4);
            __bf16* dst = &As[row * LDSPAD + q * 4];
            dst[0] = (__bf16)v.x; dst[1] = (__bf16)v.y; dst[2] = (__bf16)v.z; dst[3] = (__bf16)v.w;
        }
        #pragma unroll
        for (int j = 0; j < 4; ++j) {
            const int s = t + j * 256, row = s >> 3, q = s & 7;
            const size_t off = (size_t)(nt * 128 + row) * I_ + k0 + q * 4;
            const float4 m4 = *(const float4*)(wmean + off);
            const float4 l4 = *(const float4*)(wlogvar + off);
            const float4 n4 = *(const float4*)(nb + off);
            __bf16* dst = &Bs[row * LDSPAD + q * 4];
            dst[0] = (__bf16)(m4.x + n4.x * __expf(0.5f * l4.x));
            dst[1] = (__bf16)(m4.y + n4.y * __expf(0.5f * l4.y));
            dst[2] = (__bf16)(m4.z + n4.z * __expf(0.5f * l4.z));
            dst[3] = (__bf16)(m4.w + n4.w * __expf(0.5f * l4.w));
        }
        __syncthreads();
        bf16x8 af[4], bfr[4];
        #pragma unroll
        for (int m = 0; m < 4; ++m)
            af[m] = *(const bf16x8*)&As[(wr * 64 + m * 16 + hr) * LDSPAD + kq * 8];
        #pragma unroll
        for (int n = 0; n < 4; ++n)
            bfr[n] = *(const bf16x8*)&Bs[(wc * 64 + n * 16 + hr) * LDSPAD + kq * 8];
        #pragma unroll
        for (int m = 0; m < 4; ++m)
            #pragma unroll
            for (int n = 0; n < 4; ++n)
                acc[m][n] = __builtin_amdgcn_mfma_f32_16x16x32_bf16(af[m], bfr[n], acc[m][n], 0, 0, 0);
        __syncthreads();
    }
    float* ob = out + (size_t)b * L_ * O_;
    #pragma unroll
    for (int n = 0; n < 4; ++n) {
        const int col = nt * 128 + wc * 64 + n * 16 + hr;
        const float bv = bias[col];
        #pragma unroll
        for (int m = 0; m < 4; ++m) {
            const int row0 = mt * 128 + wr * 64 + m * 16 + kq * 4;
            #pragma unroll
            for (int j = 0; j < 4; ++j)
                ob[(size_t)(row0 + j) * O_ + col] = acc[m][n][j] + bv;
        }
    }
}

extern "C" void kernel_launch(void* const* d_in, const int* in_sizes, int n_in,
                              void* d_out, int out_size, void* d_ws, size_t ws_size,
                              hipStream_t stream) {
    const float* x       = (const float*)d_in[0];
    const float* wmean   = (const float*)d_in[1];
    const float* wlogvar = (const float*)d_in[2];
    const float* bias    = (const float*)d_in[3];
    const float* noise   = (const float*)d_in[4];
    float* out           = (float*)d_out;

    const size_t w_bytes  = (size_t)B_ * O_ * I_ * 2;   // 64 MiB
    const size_t xb_bytes = (size_t)B_ * L_ * I_ * 2;   // 32 MiB

    if (ws_size >= w_bytes + xb_bytes) {
        __bf16* W    = (__bf16*)d_ws;
        __bf16* xbuf = (__bf16*)((char*)d_ws + w_bytes);
        gen_w_kernel<<<dim3(2048), dim3(256), 0, stream>>>(wmean, wlogvar, noise, W);
        cvt_x_kernel<<<dim3(1024), dim3(256), 0, stream>>>(x, xbuf);
        gemm_8ph<<<dim3(256), dim3(512), 0, stream>>>(xbuf, W, bias, out);
    } else {
        bayes_gemm_fused<<<dim3(1024), dim3(256), 0, stream>>>(
            x, wmean, wlogvar, bias, noise, out);
    }
}

// Round 9
// 107.035 us; speedup vs baseline: 1.4226x; 1.0309x over previous
//
#include <hip/hip_runtime.h>
#include <hip/hip_bf16.h>
#include <stdint.h>

// Problem constants
#define B_ 32
#define L_ 512
#define I_ 1024
#define O_ 1024
#define NKT 16            // K-tiles of BK=64

typedef float  f32x4  __attribute__((ext_vector_type(4)));
typedef __bf16 bf16x4 __attribute__((ext_vector_type(4)));
typedef __bf16 bf16x8 __attribute__((ext_vector_type(8)));

#define CFENCE() asm volatile("" ::: "memory")
#define BARRIER() do { CFENCE(); __builtin_amdgcn_s_barrier(); CFENCE(); } while (0)

// ---- async global->LDS, 16B per lane (global_load_lds_dwordx4) ----
__device__ __forceinline__ void gload_lds16(const void* g, void* l) {
    __builtin_amdgcn_global_load_lds(
        (const __attribute__((address_space(1))) uint32_t*)(uintptr_t)g,
        (__attribute__((address_space(3))) uint32_t*)(uint32_t)(uintptr_t)l,
        16, 0, 0);
}

// ============================ Pass 1a: W = mean + eps * exp(0.5*lv) ============================
// Branchless grid-stride (R2/R5-proven ~6.2 TB/s). Do NOT merge with cvt_x (R4 regression).
__global__ void gen_w_kernel(const float* __restrict__ wmean,
                             const float* __restrict__ wlv,
                             const float* __restrict__ noise,
                             __bf16* __restrict__ W)
{
    const int n4 = B_ * O_ * I_ / 4;
    const int stride = gridDim.x * blockDim.x;
    for (int i = blockIdx.x * blockDim.x + threadIdx.x; i < n4; i += stride) {
        const int mi = i & (O_ * I_ / 4 - 1);
        const f32x4 m4 = *(const f32x4*)(wmean + (size_t)mi * 4);
        const f32x4 l4 = *(const f32x4*)(wlv   + (size_t)mi * 4);
        const f32x4 e4 = *(const f32x4*)(noise + (size_t)i  * 4);
        bf16x4 w;
        w[0] = (__bf16)(m4[0] + e4[0] * __expf(0.5f * l4[0]));
        w[1] = (__bf16)(m4[1] + e4[1] * __expf(0.5f * l4[1]));
        w[2] = (__bf16)(m4[2] + e4[2] * __expf(0.5f * l4[2]));
        w[3] = (__bf16)(m4[3] + e4[3] * __expf(0.5f * l4[3]));
        *(bf16x4*)(W + (size_t)i * 4) = w;
    }
}

// ============================ Pass 1b: x -> bf16 ============================
__global__ void cvt_x_kernel(const float* __restrict__ x, __bf16* __restrict__ xb)
{
    const int n4 = B_ * L_ * I_ / 4;
    const int stride = gridDim.x * blockDim.x;
    for (int i = blockIdx.x * blockDim.x + threadIdx.x; i < n4; i += stride) {
        const f32x4 v = *(const f32x4*)(x + (size_t)i * 4);
        bf16x4 w;
        w[0] = (__bf16)v[0]; w[1] = (__bf16)v[1];
        w[2] = (__bf16)v[2]; w[3] = (__bf16)v[3];
        *(bf16x4*)(xb + (size_t)i * 4) = w;
    }
}

// ============================ Pass 2: 256x256 8-wave GEMM, m201 8-phase schedule ============================
// K-loop identical to R8 (verified). NEW in R9: epilogue does LDS-transpose so each
// wave-instruction stores ONE FULL 1KB contiguous output row (R8 scattered 64B segments
// were ~25-30us of the 63.7us kernel).
__global__ __launch_bounds__(512, 2) void gemm_8ph(const __bf16* __restrict__ xb,
                                                   const __bf16* __restrict__ W,
                                                   const float* __restrict__ bias,
                                                   float* __restrict__ out)
{
    __shared__ __align__(16) char smem[131072];
    // K-loop: A halftile slot (d,h): (d*2+h)*16384 ; B halftile slot: 65536 + (d*2+h)*16384
    // Epilogue: reused as [64][260] f32 per round.

    // 256 blocks, XCD swizzle (256%8==0): 32 consecutive logical blocks per XCD = 4 whole batches.
    const int bid = ((int)blockIdx.x & 7) * 32 + ((int)blockIdx.x >> 3);
    const int b   = bid >> 3;
    const int mt  = (bid >> 2) & 1;
    const int nt  = bid & 3;

    const int tid  = threadIdx.x;
    const int wid  = tid >> 6, lane = tid & 63;
    const int wr   = wid >> 2;         // 0..1 (M)
    const int wc   = wid & 3;          // 0..3 (N)
    const int hr   = lane & 15;
    const int kq   = lane >> 4;

    // ---- staging geometry: thread covers phys 16B chunks tid and tid+512 of a half-tile ----
    const int P0c = tid, P1c = tid + 512;
    const int r0 = P0c >> 3, c0 = (P0c & 7) ^ (r0 & 7);   // pre-swizzled global col chunk
    const int r1 = P1c >> 3, c1 = (P1c & 7) ^ (r1 & 7);
    const size_t gO0 = (size_t)r0 * I_ + c0 * 8;
    const size_t gO1 = (size_t)r1 * I_ + c1 * 8;

    const __bf16* ax = xb + (size_t)b * L_ * I_ + (size_t)(mt * 256) * I_;
    const __bf16* bw = W  + (size_t)b * O_ * I_ + (size_t)(nt * 256) * I_;

#define STG(srcp, slotbyte) do {                                          \
        gload_lds16((srcp) + gO0, smem + (slotbyte) + tid * 16);          \
        gload_lds16((srcp) + gO1, smem + (slotbyte) + 8192 + tid * 16);   \
    } while (0)

    // ---- ds_read fragment addressing (swizzled chunk) ----
    const int pc0 = (0 + kq) ^ (hr & 7);          // kk=0 chunk
    const int pc1 = (4 + kq) ^ (hr & 7);          // kk=1 chunk
    const int aob = wr * 16384 + hr * 128;                        // region-relative
    const int bob = (wc >> 1) * 16384 + (wc & 1) * 8192 + hr * 128;  // region-relative

    f32x4 acc[8][4];
    #pragma unroll
    for (int m = 0; m < 8; ++m)
        #pragma unroll
        for (int n = 0; n < 4; ++n)
            acc[m][n] = (f32x4)(0.0f);

#define LDA(mb, dA_) do {                                                             \
        _Pragma("unroll")                                                             \
        for (int mm = 0; mm < 2; ++mm) {                                              \
            af[mm][0] = *(const bf16x8*)(smem + (dA_) + aob + ((mb)+mm)*2048 + pc0*16); \
            af[mm][1] = *(const bf16x8*)(smem + (dA_) + aob + ((mb)+mm)*2048 + pc1*16); \
        } } while (0)

#define DO_MFMA(mb) do {                                                              \
        __builtin_amdgcn_s_setprio(1);                                                \
        _Pragma("unroll")                                                             \
        for (int mm = 0; mm < 2; ++mm)                                                \
            _Pragma("unroll")                                                         \
            for (int n = 0; n < 4; ++n)                                               \
                _Pragma("unroll")                                                     \
                for (int kk = 0; kk < 2; ++kk)                                        \
                    acc[(mb)+mm][n] = __builtin_amdgcn_mfma_f32_16x16x32_bf16(        \
                        af[mm][kk], bfr[n][kk], acc[(mb)+mm][n], 0, 0, 0);            \
        __builtin_amdgcn_s_setprio(0); } while (0)

    // ---- prologue: stage B(0), A(0), B(1); wait tile-0 resident (last 2 stages in flight) ----
    STG(bw,                         65536 + 0);
    STG(bw + (size_t)128 * I_,      65536 + 16384);
    STG(ax,                         0);
    STG(ax + (size_t)128 * I_,      16384);
    STG(bw + 64,                    65536 + 32768);
    STG(bw + (size_t)128 * I_ + 64, 65536 + 32768 + 16384);
    CFENCE(); asm volatile("s_waitcnt vmcnt(4)" ::: "memory");
    BARRIER();

    for (int t = 0; t < NKT; ++t) {
        const int d  = t & 1;
        const int dA = d * 32768;
        const int dB = 65536 + d * 32768;
        const int dN = (d ^ 1) * 32768;     // A dbuf for tile t+1
        bf16x8 af[2][2], bfr[4][2];

        // ---- P0: all B frags + A m01 ; stage Ah0(t+1) ----
        #pragma unroll
        for (int n = 0; n < 4; ++n) {
            bfr[n][0] = *(const bf16x8*)(smem + dB + bob + n * 2048 + pc0 * 16);
            bfr[n][1] = *(const bf16x8*)(smem + dB + bob + n * 2048 + pc1 * 16);
        }
        LDA(0, dA);
        if (t + 1 < NKT) STG(ax + (size_t)(t + 1) * 64, dN);
        DO_MFMA(0);
        BARRIER();

        // ---- P1: A m23 ; stage Ah1(t+1) ----
        LDA(2, dA);
        if (t + 1 < NKT) STG(ax + (size_t)128 * I_ + (size_t)(t + 1) * 64, dN + 16384);
        DO_MFMA(2);
        BARRIER();

        // ---- P2: A m45 ; stage Bh0(t+2) (tile t's B fully read at P0) ----
        LDA(4, dA);
        if (t + 2 < NKT) STG(bw + (size_t)(t + 2) * 64, dB);
        DO_MFMA(4);
        BARRIER();

        // ---- P3: A m67 ; stage Bh1(t+2) ; counted vmcnt at tile boundary ----
        LDA(6, dA);
        if (t + 2 < NKT) STG(bw + (size_t)128 * I_ + (size_t)(t + 2) * 64, dB + 16384);
        DO_MFMA(6);
        if (t < NKT - 2)       { CFENCE(); asm volatile("s_waitcnt vmcnt(4)" ::: "memory"); }
        else if (t == NKT - 2) { CFENCE(); asm volatile("s_waitcnt vmcnt(0)" ::: "memory"); }
        BARRIER();
    }
#undef STG
#undef LDA
#undef DO_MFMA

    // ================= NEW epilogue: LDS transpose -> coalesced full-row stores =================
    // 4 rounds over 64-row slabs. Round r: rows mt*256 + r*64 .. +63, owned by waves with
    // wr == r>>1, acc m = (r&1)*4 + mm. LDS slab [64][260] f32 (pad kills write conflicts).
    // Store phase: each wave-instr writes ONE full 1KB row (64 lanes x float4, contiguous).
    {
        float* eb = (float*)smem;
        const f32x4 bias4 = *(const f32x4*)(bias + nt * 256 + lane * 4);  // per-lane cols, all rows
        float* ob = out + ((size_t)b * L_ + (size_t)(mt * 256)) * O_ + nt * 256;
        #pragma unroll
        for (int r = 0; r < 4; ++r) {
            BARRIER();   // previous round's LDS reads done (r=0: K-loop tail barrier already done, harmless)
            if (wr == (r >> 1)) {
                #pragma unroll
                for (int mm = 0; mm < 4; ++mm)
                    #pragma unroll
                    for (int n = 0; n < 4; ++n) {
                        const int col = wc * 64 + n * 16 + hr;
                        #pragma unroll
                        for (int j = 0; j < 4; ++j)
                            eb[(mm * 16 + kq * 4 + j) * 260 + col] = acc[(r & 1) * 4 + mm][n][j];
                    }
            }
            BARRIER();   // publish slab
            #pragma unroll
            for (int rr = 0; rr < 8; ++rr) {
                const int row = wid * 8 + rr;              // 0..63 within slab
                f32x4 v = *(const f32x4*)&eb[row * 260 + lane * 4];
                v += bias4;
                *(f32x4*)&ob[(size_t)(r * 64 + row) * O_ + lane * 4] = v;
            }
        }
    }
}

// ============================ Fallback (no workspace): R1 fused kernel ============================
#define LDSPAD 40
__global__ void bayes_gemm_fused(const float* __restrict__ x,
                                 const float* __restrict__ wmean,
                                 const float* __restrict__ wlogvar,
                                 const float* __restrict__ bias,
                                 const float* __restrict__ noise,
                                 float* __restrict__ out)
{
    __shared__ __bf16 As[128 * LDSPAD];
    __shared__ __bf16 Bs[128 * LDSPAD];
    const int bid  = blockIdx.x;
    const int b    = bid >> 5;
    const int mt   = (bid >> 3) & 3;
    const int nt   = bid & 7;
    const int t    = threadIdx.x;
    const int wave = t >> 6, lane = t & 63;
    const int wr   = wave >> 1, wc = wave & 1;
    const int hr   = lane & 15, kq = lane >> 4;
    const float* xb = x     + (size_t)b * L_ * I_;
    const float* nb = noise + (size_t)b * O_ * I_;
    f32x4 acc[4][4];
    #pragma unroll
    for (int m = 0; m < 4; ++m)
        #pragma unroll
        for (int n = 0; n < 4; ++n) acc[m][n] = (f32x4)(0.0f);
    for (int k0 = 0; k0 < I_; k0 += 32) {
        #pragma unroll
        for (int j = 0; j < 4; ++j) {
            const int s = t + j * 256, row = s >> 3, q = s & 7;
            const float4 v = *(const float4*)(xb + (size_t)(mt * 128 + row) * I_ + k0 + q * 4);
            __bf16* dst = &As[row * LDSPAD + q * 4];
            dst[0] = (__bf16)v.x; dst[1] = (__bf16)v.y; dst[2] = (__bf16)v.z; dst[3] = (__bf16)v.w;
        }
        #pragma unroll
        for (int j = 0; j < 4; ++j) {
            const int s = t + j * 256, row = s >> 3, q = s & 7;
            const size_t off = (size_t)(nt * 128 + row) * I_ + k0 + q * 4;
            const float4 m4 = *(const float4*)(wmean + off);
            const float4 l4 = *(const float4*)(wlogvar + off);
            const float4 n4 = *(const float4*)(nb + off);
            __bf16* dst = &Bs[row * LDSPAD + q * 4];
            dst[0] = (__bf16)(m4.x + n4.x * __expf(0.5f * l4.x));
            dst[1] = (__bf16)(m4.y + n4.y * __expf(0.5f * l4.y));
            dst[2] = (__bf16)(m4.z + n4.z * __expf(0.5f * l4.z));
            dst[3] = (__bf16)(m4.w + n4.w * __expf(0.5f * l4.w));
        }
        __syncthreads();
        bf16x8 af[4], bfr[4];
        #pragma unroll
        for (int m = 0; m < 4; ++m)
            af[m] = *(const bf16x8*)&As[(wr * 64 + m * 16 + hr) * LDSPAD + kq * 8];
        #pragma unroll
        for (int n = 0; n < 4; ++n)
            bfr[n] = *(const bf16x8*)&Bs[(wc * 64 + n * 16 + hr) * LDSPAD + kq * 8];
        #pragma unroll
        for (int m = 0; m < 4; ++m)
            #pragma unroll
            for (int n = 0; n < 4; ++n)
                acc[m][n] = __builtin_amdgcn_mfma_f32_16x16x32_bf16(af[m], bfr[n], acc[m][n], 0, 0, 0);
        __syncthreads();
    }
    float* ob = out + (size_t)b * L_ * O_;
    #pragma unroll
    for (int n = 0; n < 4; ++n) {
        const int col = nt * 128 + wc * 64 + n * 16 + hr;
        const float bv = bias[col];
        #pragma unroll
        for (int m = 0; m < 4; ++m) {
            const int row0 = mt * 128 + wr * 64 + m * 16 + kq * 4;
            #pragma unroll
            for (int j = 0; j < 4; ++j)
                ob[(size_t)(row0 + j) * O_ + col] = acc[m][n][j] + bv;
        }
    }
}

extern "C" void kernel_launch(void* const* d_in, const int* in_sizes, int n_in,
                              void* d_out, int out_size, void* d_ws, size_t ws_size,
                              hipStream_t stream) {
    const float* x       = (const float*)d_in[0];
    const float* wmean   = (const float*)d_in[1];
    const float* wlogvar = (const float*)d_in[2];
    const float* bias    = (const float*)d_in[3];
    const float* noise   = (const float*)d_in[4];
    float* out           = (float*)d_out;

    const size_t w_bytes  = (size_t)B_ * O_ * I_ * 2;   // 64 MiB
    const size_t xb_bytes = (size_t)B_ * L_ * I_ * 2;   // 32 MiB

    if (ws_size >= w_bytes + xb_bytes) {
        __bf16* W    = (__bf16*)d_ws;
        __bf16* xbuf = (__bf16*)((char*)d_ws + w_bytes);
        gen_w_kernel<<<dim3(2048), dim3(256), 0, stream>>>(wmean, wlogvar, noise, W);
        cvt_x_kernel<<<dim3(1024), dim3(256), 0, stream>>>(x, xbuf);
        gemm_8ph<<<dim3(256), dim3(512), 0, stream>>>(xbuf, W, bias, out);
    } else {
        bayes_gemm_fused<<<dim3(1024), dim3(256), 0, stream>>>(
            x, wmean, wlogvar, bias, noise, out);
    }
}